// Round 3
// baseline (17179.535 us; speedup 1.0000x reference)
//
#include <hip/hip_runtime.h>

typedef _Float16 f16x8 __attribute__((ext_vector_type(8)));
typedef _Float16 f16x2 __attribute__((ext_vector_type(2)));

union F16x8U { f16x8 v8; f16x2 v2[4]; };

__device__ __forceinline__ float dot2acc(f16x2 a, f16x2 b, float c) {
#if __has_builtin(__builtin_amdgcn_fdot2)
    return __builtin_amdgcn_fdot2(a, b, c, false);
#else
    return c + (float)a[0] * (float)b[0] + (float)a[1] * (float)b[1];
#endif
}

__device__ __forceinline__ float sigmoidf_(float x) {
    return __builtin_amdgcn_rcpf(1.f + __expf(-x));
}

__device__ __forceinline__ float tanhf_(float x) {
    float a = fabsf(x);
    float e = __expf(-2.f * a);
    float r = (1.f - e) * __builtin_amdgcn_rcpf(1.f + e);
    return copysignf(r, x);
}

// ---------------------------------------------------------------------------
// ws layout (bytes):
//   0         : packed fp16 weights (whhp 442368h, wihp 27648h, wih2h 18432h)
//   1048576   : sxp2   (64*2048*48 f32, 25.17 MB)
//   26214400  : exch   (64*2*384 fp16 h-exchange, double-buffered by t&1)
//   26312704  : cnt    (64*2048 u32)  h-exchange arrival counters
//   26836992  : cnt2   (64*512  u32)  xp2 group (4-step) arrival counters
// ---------------------------------------------------------------------------

// whhp chunk layout: idx = ((q*48 + k8)*3 + g)*96 + jl, chunk = 8 fp16 of
// Whh1[g*384 + q*96 + jl][k8*8 .. +7].  wihp: ((q*3+c)*3+g)*96+jl (K pad 24).
__global__ void pack_weights(const float* __restrict__ Whh1,
                             const float* __restrict__ Wih1,
                             const float* __restrict__ Wih2,
                             _Float16* __restrict__ wsbase) {
    int tid = blockIdx.x * 256 + threadIdx.x;
    if (tid < 55296) {
        int jl = tid % 96, g = (tid / 96) % 3, k8 = (tid / 288) % 48, q = tid / 13824;
        int row = g * 384 + q * 96 + jl;
        f16x8 v;
#pragma unroll
        for (int c = 0; c < 8; ++c) v[c] = (_Float16)Whh1[row * 384 + k8 * 8 + c];
        ((f16x8*)wsbase)[tid] = v;
    } else if (tid < 58752) {
        int t2 = tid - 55296;
        int jl = t2 % 96, g = (t2 / 96) % 3, c8 = (t2 / 288) % 3, q = t2 / 864;
        int row = g * 384 + q * 96 + jl;
        f16x8 v;
#pragma unroll
        for (int c = 0; c < 8; ++c) {
            int kk = c8 * 8 + c;
            v[c] = (kk < 20) ? (_Float16)Wih1[row * 20 + kk] : (_Float16)0.f;
        }
        ((f16x8*)(wsbase + 442368))[t2] = v;
    } else if (tid < 77184) {
        int t3 = tid - 58752;
        wsbase[470016 + t3] = (_Float16)Wih2[t3];
    }
}

// ---------------------------------------------------------------------------
// gru1_scan: blocks 0..255 = producers (4 j-split blocks per batch, same-XCD
// coset placement under blockIdx%8 round-robin); blocks 256..319 = GRU2+FC
// consumers (1 wave per batch) overlapping the producers via cnt2 flags.
// ---------------------------------------------------------------------------
__global__ __launch_bounds__(768) void gru1_scan(
    const float* __restrict__ x, const float* __restrict__ h1_0,
    const float* __restrict__ h2_0,
    const float* __restrict__ bih1, const float* __restrict__ bhh1,
    const _Float16* __restrict__ whhp, const _Float16* __restrict__ wihp,
    const _Float16* __restrict__ wih2h,
    const float* __restrict__ Whh2, const float* __restrict__ bih2,
    const float* __restrict__ bhh2,
    const float* __restrict__ Wfc, const float* __restrict__ bfc,
    float* __restrict__ sxp2g, unsigned* __restrict__ cnt,
    unsigned* __restrict__ cnt2, _Float16* __restrict__ exch,
    float* __restrict__ xmid, float* __restrict__ h1f_o,
    float* __restrict__ h2f_o) {
    const int bid = blockIdx.x;
    const int tid = threadIdx.x;

    if (bid >= 256) {
        // ---------------- consumer: GRU2 + ReLU + FC + 2*tanh ----------------
        if (tid >= 64) return;
        const int b = bid - 256;
        const int l = tid;
        float w2r[16]; float bx2 = 0.f, bh2 = 0.f;
        if (l < 48) {
#pragma unroll
            for (int k = 0; k < 16; ++k) w2r[k] = Whh2[l * 16 + k];
            bx2 = bih2[l]; bh2 = bhh2[l];
        }
        float wfc[16]; float bf = 0.f;
        if (l < 20) {
#pragma unroll
            for (int k = 0; k < 16; ++k) wfc[k] = Wfc[l * 16 + k];
            bf = bfc[l];
        }
        float h2 = (l < 16) ? h2_0[b * 16 + l] : 0.f;
        float* xm = xmid + (size_t)b * 40960;
        const float* sx = sxp2g + (size_t)b * 2048 * 48;
        for (int tg = 0; tg < 512; ++tg) {
            while (__hip_atomic_load(&cnt2[b * 512 + tg], __ATOMIC_ACQUIRE,
                                     __HIP_MEMORY_SCOPE_AGENT) < 4u)
                __builtin_amdgcn_s_sleep(2);
#pragma unroll
            for (int tq = 0; tq < 4; ++tq) {
                int t = tg * 4 + tq;
                float ax = (l < 48) ? sx[(size_t)t * 48 + l] + bx2 : 0.f;
                float ah = bh2;
#pragma unroll
                for (int k = 0; k < 16; ++k) ah += __shfl(h2, k) * w2r[k];
                float s_   = ax + ah;
                float zpre = __shfl(s_, (16 + l) & 63);
                float xn3  = __shfl(ax, (32 + l) & 63);
                float ghn  = __shfl(ah, (32 + l) & 63);
                float r2 = sigmoidf_(s_);
                float z2 = sigmoidf_(zpre);
                float n2 = tanhf_(xn3 + r2 * ghn);
                float h2n = (1.f - z2) * n2 + z2 * h2;
                if (l < 16) h2 = h2n;
                float y2 = fmaxf(h2n, 0.f);
                float a = bf;
#pragma unroll
                for (int k = 0; k < 16; ++k) a += __shfl(y2, k) * wfc[k];
                if (l < 20) xm[t * 20 + l] = 2.f * tanhf_(a);
            }
        }
        if (l < 16) h2f_o[b * 16 + l] = h2;
        return;
    }

    // ------------------------------ producer ------------------------------
    // bid = xcd + 8*m; m = row*4 + q; batch b = xcd + 8*row  (same-XCD coset)
    const int xcd = bid & 7, m = bid >> 3, q = m & 3, row = m >> 2;
    const int b = xcd + 8 * row;
    const int ko = tid / 96;          // 0..7, K-octant (6 k8-chunks each)
    const int jl = tid - ko * 96;     // 0..95, local gate index

    __shared__ __align__(16) _Float16 h1h[384];
    __shared__ __align__(16) _Float16 hhist[4][384];
    __shared__ __align__(16) _Float16 xsh[2][24];
    __shared__ __align__(16) float4 part4[96 * 8];   // XOR-swizzled slots
    __shared__ float part2[4 * 12 * 65];             // xp2 partials (+1 pad)

    float cbr = 0.f, cbz = 0.f, cxn = 0.f, chn = 0.f, hprev = 0.f;
    if (tid < 96) {
        int j = q * 96 + tid;
        cbr = bih1[j] + bhh1[j];
        cbz = bih1[384 + j] + bhh1[384 + j];
        cxn = bih1[768 + j];
        chn = bhh1[768 + j];
        hprev = h1_0[b * 384 + j];
    }
    if (tid < 384) h1h[tid] = (_Float16)h1_0[b * 384 + tid];
    const float* xb = x + (size_t)b * 40960;
    if (tid < 24) {
        xsh[0][tid] = (_Float16)((tid < 20) ? xb[tid] : 0.f);
        xsh[1][tid] = (_Float16)0.f;
    }
    __syncthreads();

    const f16x8* Whb = (const f16x8*)whhp + q * 13824 + ko * 1728 + jl;
    const bool xp = (ko == 1 || ko == 3 || ko == 5);
    const f16x8* Wib = (const f16x8*)wihp + q * 864 + (ko >> 1) * 288 + jl;
    const f16x8* hcc = (const f16x8*)h1h;
    const int pslot = jl * 8 + (ko ^ (jl & 7));
    const int o2 = tid >> 6, ks = tid & 63;   // xp2 mapping
    const _Float16* w2row = wih2h + (q * 12 + o2) * 384 + ks * 6;

    for (int t = 0; t < 2048; ++t) {
        // ---- main partial dots (own K-octant, 3 gates) ----
        float ar = 0.f, az = 0.f, ahn = 0.f, axn = 0.f;
#pragma unroll
        for (int mm = 0; mm < 6; ++mm) {
            F16x8U hv; hv.v8 = hcc[ko * 6 + mm];
            F16x8U wr, wz, wn;
            wr.v8 = Whb[mm * 288];
            wz.v8 = Whb[mm * 288 + 96];
            wn.v8 = Whb[mm * 288 + 192];
#pragma unroll
            for (int i = 0; i < 4; ++i) {
                ar  = dot2acc(wr.v2[i], hv.v2[i], ar);
                az  = dot2acc(wz.v2[i], hv.v2[i], az);
                ahn = dot2acc(wn.v2[i], hv.v2[i], ahn);
            }
        }
        if (xp) {
            F16x8U xv; xv.v8 = *(const f16x8*)(xsh[t & 1] + (ko >> 1) * 8);
            F16x8U wr, wz, wn;
            wr.v8 = Wib[0];
            wz.v8 = Wib[96];
            wn.v8 = Wib[192];
#pragma unroll
            for (int i = 0; i < 4; ++i) {
                ar  = dot2acc(wr.v2[i], xv.v2[i], ar);
                az  = dot2acc(wz.v2[i], xv.v2[i], az);
                axn = dot2acc(wn.v2[i], xv.v2[i], axn);
            }
        }
        part4[pslot] = make_float4(ar, az, ahn, axn);
        __syncthreads();  // S1

        // ---- finalize own 96 h, publish to exchange ----
        if (tid < 96) {
            float sr = cbr, sz = cbz, snh = chn, snx = cxn;
            const int base = tid * 8, sw = tid & 7;
#pragma unroll
            for (int kk = 0; kk < 8; ++kk) {
                float4 p = part4[base + (kk ^ sw)];
                sr += p.x; sz += p.y; snh += p.z; snx += p.w;
            }
            float r = sigmoidf_(sr), z = sigmoidf_(sz);
            float n = tanhf_(snx + r * snh);
            hprev = (1.f - z) * n + z * hprev;
            exch[((size_t)b * 2 + (t & 1)) * 384 + q * 96 + tid] = (_Float16)hprev;
        }
        if (tid >= 96 && tid < 116 && t + 1 < 2048)
            xsh[(t + 1) & 1][tid - 96] = (_Float16)xb[(t + 1) * 20 + (tid - 96)];
        __syncthreads();  // S2

        if (tid == 0)
            __hip_atomic_fetch_add(&cnt[b * 2048 + t], 1u, __ATOMIC_RELEASE,
                                   __HIP_MEMORY_SCOPE_AGENT);
        if (tid < 64) {
            while (__hip_atomic_load(&cnt[b * 2048 + t], __ATOMIC_ACQUIRE,
                                     __HIP_MEMORY_SCOPE_AGENT) < 4u) { }
            if (tid < 48) {
                f16x8 hv = ((const f16x8*)(exch + ((size_t)b * 2 + (t & 1)) * 384))[tid];
                ((f16x8*)h1h)[tid] = hv;
                ((f16x8*)hhist[t & 3])[tid] = hv;
            }
        }
        __syncthreads();  // S3: h_t in h1h (next step's input) + hhist

        // ---- xp2 (GRU2 input proj), batched every 4 steps ----
        if ((t & 3) == 3) {
            f16x2 w0 = *(const f16x2*)(w2row);
            f16x2 w1 = *(const f16x2*)(w2row + 2);
            f16x2 w2 = *(const f16x2*)(w2row + 4);
#pragma unroll
            for (int tq = 0; tq < 4; ++tq) {
                const _Float16* hrow = hhist[tq] + ks * 6;
                float a = dot2acc(w0, *(const f16x2*)hrow, 0.f);
                a = dot2acc(w1, *(const f16x2*)(hrow + 2), a);
                a = dot2acc(w2, *(const f16x2*)(hrow + 4), a);
                part2[(tq * 12 + o2) * 65 + ks] = a;
            }
            __syncthreads();  // S4
            if (tid < 48) {
                int tq = tid / 12, o = tid % 12;
                const float* pr = &part2[(tq * 12 + o) * 65];
                float s0 = 0.f, s1 = 0.f, s2 = 0.f, s3 = 0.f;
#pragma unroll
                for (int i2 = 0; i2 < 16; ++i2) {
                    s0 += pr[i2 * 4];     s1 += pr[i2 * 4 + 1];
                    s2 += pr[i2 * 4 + 2]; s3 += pr[i2 * 4 + 3];
                }
                sxp2g[((size_t)b * 2048 + (t - 3 + tq)) * 48 + q * 12 + o] =
                    (s0 + s1) + (s2 + s3);
            }
            if (tid == 0)
                __hip_atomic_fetch_add(&cnt2[b * 512 + (t >> 2)], 1u,
                                       __ATOMIC_RELEASE, __HIP_MEMORY_SCOPE_AGENT);
        }
    }
    if (tid < 96) h1f_o[b * 384 + q * 96 + tid] = hprev;
}

// ---------------------------------------------------------------------------
// GRU3 on flip(x_mid): one wave per batch; x_out = tanh(y3).
// ---------------------------------------------------------------------------
__global__ __launch_bounds__(64) void gru3_bwd(
    const float* __restrict__ xmid, const float* __restrict__ h3_0,
    const float* __restrict__ Wih3, const float* __restrict__ Whh3,
    const float* __restrict__ bih3, const float* __restrict__ bhh3,
    float* __restrict__ xout, float* __restrict__ h3f_o) {
    const int b = blockIdx.x;
    const int l = threadIdx.x;

    float wi[20], wh[20];
    float bx = 0.f, bh = 0.f;
    if (l < 60) {
#pragma unroll
        for (int k = 0; k < 20; ++k) {
            wi[k] = Wih3[l * 20 + k];
            wh[k] = Whh3[l * 20 + k];
        }
        bx = bih3[l];
        bh = bhh3[l];
    }
    float h3 = (l < 20) ? h3_0[b * 20 + l] : 0.f;
    const float* xm = xmid + (size_t)b * 40960;
    float* xo = xout + (size_t)b * 40960;
    float xv = (l < 20) ? xm[2047 * 20 + l] : 0.f;

    for (int t = 2047; t >= 0; --t) {
        float xnx = (l < 20 && t > 0) ? xm[(t - 1) * 20 + l] : 0.f;
        float ax = bx, ah = bh;
#pragma unroll
        for (int k = 0; k < 20; ++k) {
            ax += __shfl(xv, k) * wi[k];
            ah += __shfl(h3, k) * wh[k];
        }
        float s_   = ax + ah;
        float zpre = __shfl(s_, (20 + l) & 63);
        float xn_  = __shfl(ax, (40 + l) & 63);
        float ghn  = __shfl(ah, (40 + l) & 63);
        float r = sigmoidf_(s_);
        float z = sigmoidf_(zpre);
        float n = tanhf_(xn_ + r * ghn);
        float hn = (1.f - z) * n + z * h3;
        if (l < 20) {
            h3 = hn;
            xo[(2047 - t) * 20 + l] = tanhf_(hn);
        }
        xv = xnx;
    }
    if (l < 20) h3f_o[b * 20 + l] = h3;
}

extern "C" void kernel_launch(void* const* d_in, const int* in_sizes, int n_in,
                              void* d_out, int out_size, void* d_ws, size_t ws_size,
                              hipStream_t stream) {
    const float* x    = (const float*)d_in[0];
    const float* h1   = (const float*)d_in[1];
    const float* h2   = (const float*)d_in[2];
    const float* h3   = (const float*)d_in[3];
    const float* Wih1 = (const float*)d_in[4];
    const float* Whh1 = (const float*)d_in[5];
    const float* bih1 = (const float*)d_in[6];
    const float* bhh1 = (const float*)d_in[7];
    const float* Wih2 = (const float*)d_in[8];
    const float* Whh2 = (const float*)d_in[9];
    const float* bih2 = (const float*)d_in[10];
    const float* bhh2 = (const float*)d_in[11];
    const float* Wih3 = (const float*)d_in[12];
    const float* Whh3 = (const float*)d_in[13];
    const float* bih3 = (const float*)d_in[14];
    const float* bhh3 = (const float*)d_in[15];
    const float* Wfc  = (const float*)d_in[16];
    const float* bfc  = (const float*)d_in[17];

    float* out  = (float*)d_out;
    float* xmid = out;                  // (64,2048,20)
    float* xout = out + 2621440;        // (64,2048,20)
    float* h1f  = out + 5242880;        // (64,384)
    float* h2f  = out + 5267456;        // (64,16)
    float* h3f  = out + 5268480;        // (64,20)

    char* ws = (char*)d_ws;
    _Float16* wsh  = (_Float16*)ws;
    float*    sxp2 = (float*)(ws + 1048576);
    _Float16* exch = (_Float16*)(ws + 26214400);
    unsigned* cnt  = (unsigned*)(ws + 26312704);
    unsigned* cnt2 = (unsigned*)(ws + 26836992);

    hipMemsetAsync(ws + 26312704, 0, 655360, stream);
    pack_weights<<<302, 256, 0, stream>>>(Whh1, Wih1, Wih2, wsh);
    gru1_scan<<<320, 768, 0, stream>>>(x, h1, h2, bih1, bhh1,
                                       wsh, wsh + 442368, wsh + 470016,
                                       Whh2, bih2, bhh2, Wfc, bfc,
                                       sxp2, cnt, cnt2, exch,
                                       xmid, h1f, h2f);
    gru3_bwd<<<64, 64, 0, stream>>>(xmid, h3, Wih3, Whh3, bih3, bhh3,
                                    xout, h3f);
}

// Round 4
// 6623.978 us; speedup vs baseline: 2.5935x; 2.5935x over previous
//
#include <hip/hip_runtime.h>

typedef _Float16 f16x8 __attribute__((ext_vector_type(8)));
typedef _Float16 f16x2 __attribute__((ext_vector_type(2)));

union F16x8U { f16x8 v8; f16x2 v2[4]; };
union FP16U { _Float16 h; unsigned short u; };

__device__ __forceinline__ float dot2acc(f16x2 a, f16x2 b, float c) {
#if __has_builtin(__builtin_amdgcn_fdot2)
    return __builtin_amdgcn_fdot2(a, b, c, false);
#else
    return c + (float)a[0] * (float)b[0] + (float)a[1] * (float)b[1];
#endif
}

__device__ __forceinline__ float sigmoidf_(float x) {
    return __builtin_amdgcn_rcpf(1.f + __expf(-x));
}

__device__ __forceinline__ float tanhf_(float x) {
    float a = fabsf(x);
    float e = __expf(-2.f * a);
    float r = (1.f - e) * __builtin_amdgcn_rcpf(1.f + e);
    return copysignf(r, x);
}

// ---------------------------------------------------------------------------
// ws layout (bytes):
//   0         : whhp  55296 f16x8 chunks (884736 B) — per-thread reg layout
//   884736    : wih1p 3456 f16x8 chunks (55296 B)
//   940032    : wih2h 18432 fp16 (36864 B)
//   1048576   : sxp2  (64*2048*48 f32, 25.17 MB)
//   26214400  : exch  (2 buffers * 64*384 u32 tagged fp16, 196608 B)
// ---------------------------------------------------------------------------

// whhp chunk idx = ((q*8+ko)*96 + jl)*18 + g*6 + m : Whh1[g*384+q*96+jl][ko*48+m*8 ..+7]
// wih1p chunk idx = ((q*3+g)*96 + jl)*3 + m        : Wih1[g*384+q*96+jl][m*8 ..+7] (K pad 24)
__global__ void pack_weights(const float* __restrict__ Whh1,
                             const float* __restrict__ Wih1,
                             const float* __restrict__ Wih2,
                             _Float16* __restrict__ wsbase) {
    int tid = blockIdx.x * 256 + threadIdx.x;
    f16x8* whhp  = (f16x8*)wsbase;
    f16x8* wih1p = (f16x8*)(wsbase + 442368);
    _Float16* wih2h = wsbase + 470016;
    if (tid < 55296) {
        int c = tid % 18, thr = tid / 18;
        int g = c / 6, m = c % 6;
        int jl = thr % 96, ko = (thr / 96) % 8, q = thr / 768;
        int row = g * 384 + q * 96 + jl;
        int kb = ko * 48 + m * 8;
        f16x8 v;
#pragma unroll
        for (int i = 0; i < 8; ++i) v[i] = (_Float16)Whh1[row * 384 + kb + i];
        whhp[tid] = v;
    } else if (tid < 58752) {
        int t2 = tid - 55296;
        int m = t2 % 3, thr = t2 / 3;
        int jl = thr % 96, g = (thr / 96) % 3, q = thr / 288;
        int row = g * 384 + q * 96 + jl;
        f16x8 v;
#pragma unroll
        for (int i = 0; i < 8; ++i) {
            int kk = m * 8 + i;
            v[i] = (kk < 20) ? (_Float16)Wih1[row * 20 + kk] : (_Float16)0.f;
        }
        wih1p[t2] = v;
    } else if (tid < 77184) {
        int t3 = tid - 58752;
        wih2h[t3] = (_Float16)Wih2[t3];
    }
}

// ---------------------------------------------------------------------------
// gru1_scan: 256 blocks, 4 per batch (q = j-quarter). Whh1/Wih1 slices live
// in REGISTERS for the whole scan (zero per-step weight traffic). Per-step
// h-exchange via per-word tagged relaxed atomics (no cache inv/wb).
// ---------------------------------------------------------------------------
__global__ __launch_bounds__(768, 3) void gru1_scan(
    const float* __restrict__ x, const float* __restrict__ h1_0,
    const float* __restrict__ bih1, const float* __restrict__ bhh1,
    const f16x8* __restrict__ whhp, const f16x8* __restrict__ wih1p,
    const _Float16* __restrict__ wih2h,
    float* __restrict__ sxp2g, unsigned* __restrict__ exch,
    float* __restrict__ h1f_o) {
    const int bid = blockIdx.x;
    const int b = bid >> 2, q = bid & 3;
    const int tid = threadIdx.x;
    const int ko = tid / 96, jl = tid % 96;

    __shared__ __align__(16) _Float16 h1h[384];
    __shared__ __align__(16) _Float16 hhist[4][384];
    __shared__ __align__(16) _Float16 xsh[2][24];
    __shared__ __align__(16) float4 part4[8 * 96];
    __shared__ float part2[4 * 12 * 65];

    // ---- weights into registers ----
    F16x8U W[18];
    {
        const f16x8* wp = whhp + ((size_t)((q * 8 + ko) * 96 + jl)) * 18;
#pragma unroll
        for (int c = 0; c < 18; ++c) W[c].v8 = wp[c];
    }
    F16x8U Wx[3];
    if (ko < 3) {
        const f16x8* wp = wih1p + ((size_t)((q * 3 + ko) * 96 + jl)) * 3;
#pragma unroll
        for (int c = 0; c < 3; ++c) Wx[c].v8 = wp[c];
    }

    float cbr = 0.f, cbz = 0.f, cxn = 0.f, chn = 0.f, hprev = 0.f;
    if (tid < 96) {
        int j = q * 96 + tid;
        cbr = bih1[j] + bhh1[j];
        cbz = bih1[384 + j] + bhh1[384 + j];
        cxn = bih1[768 + j];
        chn = bhh1[768 + j];
        hprev = h1_0[b * 384 + j];
    }
    if (tid < 384) h1h[tid] = (_Float16)h1_0[b * 384 + tid];
    const float* xb = x + (size_t)b * 40960;
    if (tid < 24) {
        xsh[0][tid] = (_Float16)((tid < 20) ? xb[tid] : 0.f);
        xsh[1][tid] = (_Float16)0.f;
    }

    unsigned* exb0 = exch + (size_t)b * 384;
    unsigned* exb1 = exch + 24576 + (size_t)b * 384;
    const int rs = tid - 384;  // gather threads: 384..671
    const int gslot = (rs >= 0 && rs < 288) ? ((q * 96 + 96 + rs) % 384) : 0;

    const int o2 = tid >> 6, ks = tid & 63;
    const _Float16* w2row = wih2h + (q * 12 + o2) * 384 + ks * 6;

    __syncthreads();

    for (int t = 0; t < 2048; ++t) {
        // ---- P1: partial gate dots from registers ----
        float ar = 0.f, az = 0.f, ahn = 0.f, axn = 0.f;
        const _Float16* hbase = h1h + ko * 48;
#pragma unroll
        for (int m = 0; m < 6; ++m) {
            F16x8U hv; hv.v8 = *(const f16x8*)(hbase + m * 8);
#pragma unroll
            for (int i = 0; i < 4; ++i) {
                ar  = dot2acc(W[m].v2[i],      hv.v2[i], ar);
                az  = dot2acc(W[6 + m].v2[i],  hv.v2[i], az);
                ahn = dot2acc(W[12 + m].v2[i], hv.v2[i], ahn);
            }
        }
        if (ko < 3) {
            float acc = 0.f;
            const _Float16* xs = xsh[t & 1];
#pragma unroll
            for (int m = 0; m < 3; ++m) {
                F16x8U xv; xv.v8 = *(const f16x8*)(xs + m * 8);
#pragma unroll
                for (int i = 0; i < 4; ++i)
                    acc = dot2acc(Wx[m].v2[i], xv.v2[i], acc);
            }
            if (ko == 0) ar += acc;
            else if (ko == 1) az += acc;
            else axn += acc;
        }
        part4[ko * 96 + jl] = make_float4(ar, az, ahn, axn);
        __syncthreads();  // S1

        const unsigned tag = (unsigned)(t + 1);
        unsigned* exw = ((t + 1) & 1) ? exb1 : exb0;
        if (tid < 96) {
            float sr = cbr, sz = cbz, snh = chn, snx = cxn;
#pragma unroll
            for (int k = 0; k < 8; ++k) {
                float4 p = part4[k * 96 + tid];
                sr += p.x; sz += p.y; snh += p.z; snx += p.w;
            }
            float r = sigmoidf_(sr), z = sigmoidf_(sz);
            float n = tanhf_(snx + r * snh);
            hprev = (1.f - z) * n + z * hprev;
            FP16U hu; hu.h = (_Float16)hprev;
            __hip_atomic_store(&exw[q * 96 + tid], (tag << 16) | (unsigned)hu.u,
                               __ATOMIC_RELAXED, __HIP_MEMORY_SCOPE_AGENT);
            h1h[q * 96 + tid] = hu.h;
            hhist[t & 3][q * 96 + tid] = hu.h;
        }
        if (tid >= 96 && tid < 116 && t + 1 < 2048)
            xsh[(t + 1) & 1][tid - 96] = (_Float16)xb[(t + 1) * 20 + (tid - 96)];
        if (tid >= 384 && tid < 672) {
            unsigned w;
            do {
                w = __hip_atomic_load(&exw[gslot], __ATOMIC_RELAXED,
                                      __HIP_MEMORY_SCOPE_AGENT);
            } while ((w >> 16) != tag);
            FP16U hu; hu.u = (unsigned short)(w & 0xffffu);
            h1h[gslot] = hu.h;
            hhist[t & 3][gslot] = hu.h;
        }
        __syncthreads();  // S2: h_{t+1} complete in h1h

        // ---- xp2 (GRU2 input proj), batched every 4 steps ----
        if ((t & 3) == 3) {
            f16x2 w0 = *(const f16x2*)(w2row);
            f16x2 w1 = *(const f16x2*)(w2row + 2);
            f16x2 w2 = *(const f16x2*)(w2row + 4);
#pragma unroll
            for (int tq = 0; tq < 4; ++tq) {
                const _Float16* hrow = hhist[tq] + ks * 6;
                float a = dot2acc(w0, *(const f16x2*)hrow, 0.f);
                a = dot2acc(w1, *(const f16x2*)(hrow + 2), a);
                a = dot2acc(w2, *(const f16x2*)(hrow + 4), a);
                part2[(tq * 12 + o2) * 65 + ks] = a;
            }
            __syncthreads();  // S3
            if (tid < 48) {
                int tq = tid / 12, o = tid % 12;
                const float* pr = &part2[(tq * 12 + o) * 65];
                float s0 = 0.f, s1 = 0.f, s2 = 0.f, s3 = 0.f;
#pragma unroll
                for (int i2 = 0; i2 < 16; ++i2) {
                    s0 += pr[i2 * 4];     s1 += pr[i2 * 4 + 1];
                    s2 += pr[i2 * 4 + 2]; s3 += pr[i2 * 4 + 3];
                }
                __hip_atomic_store(
                    &sxp2g[((size_t)b * 2048 + (t - 3 + tq)) * 48 + q * 12 + o],
                    (s0 + s1) + (s2 + s3), __ATOMIC_RELAXED,
                    __HIP_MEMORY_SCOPE_AGENT);
            }
        }
    }
    if (tid < 96) h1f_o[b * 384 + q * 96 + tid] = hprev;
}

// ---------------------------------------------------------------------------
// Tail: GRU2+ReLU+FC forward (from sxp2), then GRU3 reverse. One wave per
// batch, shuffles only; 4-deep register prefetch pipelines hide load latency.
// ---------------------------------------------------------------------------
__global__ __launch_bounds__(64) void tail_scan(
    const float* __restrict__ sxp2g, const float* __restrict__ h2_0,
    const float* __restrict__ h3_0,
    const float* __restrict__ Whh2, const float* __restrict__ bih2,
    const float* __restrict__ bhh2,
    const float* __restrict__ Wfc, const float* __restrict__ bfc,
    const float* __restrict__ Wih3, const float* __restrict__ Whh3,
    const float* __restrict__ bih3, const float* __restrict__ bhh3,
    float* __restrict__ xmid, float* __restrict__ xout,
    float* __restrict__ h2f_o, float* __restrict__ h3f_o) {
    const int b = blockIdx.x;
    const int l = threadIdx.x;

    // ---- loop 1: GRU2 + ReLU + FC + 2*tanh ----
    float w2r[16]; float bx2 = 0.f, bh2 = 0.f;
    if (l < 48) {
#pragma unroll
        for (int k = 0; k < 16; ++k) w2r[k] = Whh2[l * 16 + k];
        bx2 = bih2[l]; bh2 = bhh2[l];
    }
    float wfc[16]; float bf = 0.f;
    if (l < 20) {
#pragma unroll
        for (int k = 0; k < 16; ++k) wfc[k] = Wfc[l * 16 + k];
        bf = bfc[l];
    }
    float h2 = (l < 16) ? h2_0[b * 16 + l] : 0.f;
    float* xm = xmid + (size_t)b * 40960;
    const float* sx = sxp2g + (size_t)b * 2048 * 48;

    float pre[4];
#pragma unroll
    for (int i = 0; i < 4; ++i) pre[i] = (l < 48) ? sx[i * 48 + l] : 0.f;

    for (int tg = 0; tg < 512; ++tg) {
#pragma unroll
        for (int tq = 0; tq < 4; ++tq) {
            const int t = tg * 4 + tq;
            float ax = pre[tq] + bx2;
            if (l < 48 && t + 4 < 2048) pre[tq] = sx[(size_t)(t + 4) * 48 + l];
            float ah = bh2;
#pragma unroll
            for (int k = 0; k < 16; ++k) ah += __shfl(h2, k) * w2r[k];
            float s_   = ax + ah;
            float zpre = __shfl(s_, (16 + l) & 63);
            float xn3  = __shfl(ax, (32 + l) & 63);
            float ghn  = __shfl(ah, (32 + l) & 63);
            float r2 = sigmoidf_(s_);
            float z2 = sigmoidf_(zpre);
            float n2 = tanhf_(xn3 + r2 * ghn);
            float h2n = (1.f - z2) * n2 + z2 * h2;
            if (l < 16) h2 = h2n;
            float y2 = fmaxf(h2n, 0.f);
            float a = bf;
#pragma unroll
            for (int k = 0; k < 16; ++k) a += __shfl(y2, k) * wfc[k];
            if (l < 20) xm[t * 20 + l] = 2.f * tanhf_(a);
        }
    }
    if (l < 16) h2f_o[b * 16 + l] = h2;

    // ---- loop 2: GRU3 on reversed xmid ----
    float wi3[20], wh3[20]; float bx3 = 0.f, bh3 = 0.f;
    if (l < 60) {
#pragma unroll
        for (int k = 0; k < 20; ++k) {
            wi3[k] = Wih3[l * 20 + k];
            wh3[k] = Whh3[l * 20 + k];
        }
        bx3 = bih3[l]; bh3 = bhh3[l];
    }
    float h3 = (l < 20) ? h3_0[b * 20 + l] : 0.f;
    float* xo = xout + (size_t)b * 40960;

    float prx[4];
#pragma unroll
    for (int i = 0; i < 4; ++i) prx[i] = (l < 20) ? xm[(2047 - i) * 20 + l] : 0.f;

    for (int tg = 0; tg < 512; ++tg) {
#pragma unroll
        for (int tq = 0; tq < 4; ++tq) {
            const int t = 2047 - (tg * 4 + tq);
            float xv = prx[tq];
            if (l < 20 && t - 4 >= 0) prx[tq] = xm[(t - 4) * 20 + l];
            float ax = bx3, ah = bh3;
#pragma unroll
            for (int k = 0; k < 20; ++k) {
                ax += __shfl(xv, k) * wi3[k];
                ah += __shfl(h3, k) * wh3[k];
            }
            float s_   = ax + ah;
            float zpre = __shfl(s_, (20 + l) & 63);
            float xn_  = __shfl(ax, (40 + l) & 63);
            float ghn  = __shfl(ah, (40 + l) & 63);
            float r = sigmoidf_(s_);
            float z = sigmoidf_(zpre);
            float n = tanhf_(xn_ + r * ghn);
            float hn = (1.f - z) * n + z * h3;
            if (l < 20) {
                h3 = hn;
                xo[(2047 - t) * 20 + l] = tanhf_(hn);
            }
        }
    }
    if (l < 20) h3f_o[b * 20 + l] = h3;
}

extern "C" void kernel_launch(void* const* d_in, const int* in_sizes, int n_in,
                              void* d_out, int out_size, void* d_ws, size_t ws_size,
                              hipStream_t stream) {
    const float* x    = (const float*)d_in[0];
    const float* h1   = (const float*)d_in[1];
    const float* h2   = (const float*)d_in[2];
    const float* h3   = (const float*)d_in[3];
    const float* Wih1 = (const float*)d_in[4];
    const float* Whh1 = (const float*)d_in[5];
    const float* bih1 = (const float*)d_in[6];
    const float* bhh1 = (const float*)d_in[7];
    const float* Wih2 = (const float*)d_in[8];
    const float* Whh2 = (const float*)d_in[9];
    const float* bih2 = (const float*)d_in[10];
    const float* bhh2 = (const float*)d_in[11];
    const float* Wih3 = (const float*)d_in[12];
    const float* Whh3 = (const float*)d_in[13];
    const float* bih3 = (const float*)d_in[14];
    const float* bhh3 = (const float*)d_in[15];
    const float* Wfc  = (const float*)d_in[16];
    const float* bfc  = (const float*)d_in[17];

    float* out  = (float*)d_out;
    float* xmid = out;                  // (64,2048,20)
    float* xout = out + 2621440;        // (64,2048,20)
    float* h1f  = out + 5242880;        // (64,384)
    float* h2f  = out + 5267456;        // (64,16)
    float* h3f  = out + 5268480;        // (64,20)

    char* ws = (char*)d_ws;
    _Float16* wsh  = (_Float16*)ws;
    float*    sxp2 = (float*)(ws + 1048576);
    unsigned* exch = (unsigned*)(ws + 26214400);

    hipMemsetAsync(exch, 0, 196608, stream);  // tags := 0 (never matches 1..2048)
    pack_weights<<<302, 256, 0, stream>>>(Whh1, Wih1, Wih2, wsh);
    gru1_scan<<<256, 768, 0, stream>>>(x, h1, bih1, bhh1,
                                       (const f16x8*)wsh,
                                       (const f16x8*)(wsh + 442368),
                                       wsh + 470016,
                                       sxp2, exch, h1f);
    tail_scan<<<64, 64, 0, stream>>>(sxp2, h2, h3,
                                     Whh2, bih2, bhh2, Wfc, bfc,
                                     Wih3, Whh3, bih3, bhh3,
                                     xmid, xout, h2f, h3f);
}